// Round 3
// baseline (310.540 us; speedup 1.0000x reference)
//
#include <hip/hip_runtime.h>
#include <math.h>

#define NVARS 512
#define HID   16
#define TOPK  8
#define MAGIC0 0x5eedf00du
#define MAGIC1 0xa11ca11eu

// ---------------- Fused kernel: routing (blocks 0..63) + gather-apply --------
// R7. Post-mortems: R5 (barrier restructure) neutral -> apply not latency/
// barrier bound (32 waves/CU hide it). R6 (b64 16-bank-class gather) +5.5us,
// matching the +2048 LDS-instr/CU issue cost -> b128 gather conflicts are
// ~free (random max-bucket ~= the 12cyc b128 bytes-floor); LDS cost = issue
// count, and R5's 64 b128 reads/thread-tile is the floor. Apply internals are
// at their pipe bound. Remaining controllable cost is STRUCTURAL: the serial
// routing kernel (~4-5us on 64 CUs while 192 idle) + one launch gap.
// Fix: single launch, exactly-resident grid (1024 blocks x 512 thr,
// __launch_bounds__(512,8) => VGPR<=64, LDS 34KB => 4 blocks/CU x 256 CU =
// 1024: ALL blocks co-resident at t0, so producer/consumer flag-spin cannot
// deadlock regardless of dispatch order). Blocks 0..63 compute routing for
// rows 8b..8b+7, publish with __threadfence + device-scope atomicExch of TWO
// magic words (ws is poisoned; dual-magic ~eliminates false "ready").
// Everyone issues group-0 x loads BEFORE routing/spin -> HBM streaming starts
// at t=0, routing overlaps it. Spin: threads t<64 (one per chunk) + barrier +
// acquire fence. Apply body = R5's known-good b128 structure, unchanged.
__global__ __launch_bounds__(512, 8) void fused_kernel(
    const float* __restrict__ x,     // (32768, 512)
    const float* __restrict__ ve,    // (512,16)
    const float* __restrict__ Wq,    // (16,16)
    const float* __restrict__ bq,    // (16,)
    const float* __restrict__ Wk,    // (16,16)
    const float* __restrict__ bk,    // (16,)
    int*   __restrict__ g_idx,       // ws: (512,8)
    float* __restrict__ g_w,         // ws: (512,8)
    unsigned* __restrict__ flags,    // ws: (128,)
    float* __restrict__ out)         // (32768, 512)
{
    // union: routing Ks[512][17] (34816 B)  /  apply xs[2][2][512] float4 (32768 B)
    __shared__ __align__(16) unsigned char smem[NVARS * (HID + 1) * 4];

    const int t = threadIdx.x;       // 0..511

    // ---- issue group-0 staging loads FIRST (independent of routing) ----
    const long base = (long)blockIdx.x * 32;
    const float* xp = x + base * NVARS + t;
    float v0 = xp[0 * NVARS];
    float v1 = xp[1 * NVARS];
    float v2 = xp[2 * NVARS];
    float v3 = xp[3 * NVARS];
    float v4 = xp[4 * NVARS];
    float v5 = xp[5 * NVARS];
    float v6 = xp[6 * NVARS];
    float v7 = xp[7 * NVARS];

    // ---- producer blocks: routing for rows blockIdx.x*8 .. +7 ----
    if (blockIdx.x < 64) {
        float (*Ks)[HID + 1] = reinterpret_cast<float (*)[HID + 1]>(smem);
        const int wave = t >> 6;
        const int lane = t & 63;
        const int n    = blockIdx.x * 8 + wave;

        float vrow[HID];
        #pragma unroll
        for (int j = 0; j < HID; ++j) vrow[j] = ve[t * HID + j];
        #pragma unroll
        for (int h = 0; h < HID; ++h) {
            float s = bk[h];
            #pragma unroll
            for (int j = 0; j < HID; ++j) s += vrow[j] * Wk[h * HID + j];
            Ks[t][h] = s;
        }

        float q[HID];
        #pragma unroll
        for (int j = 0; j < HID; ++j) vrow[j] = ve[n * HID + j];
        #pragma unroll
        for (int h = 0; h < HID; ++h) {
            float s = bq[h];
            #pragma unroll
            for (int j = 0; j < HID; ++j) s += vrow[j] * Wq[h * HID + j];
            q[h] = s;
        }

        __syncthreads();

        float vals[8];
        #pragma unroll
        for (int i = 0; i < 8; ++i) {
            const int m = i * 64 + lane;
            float s = 0.f;
            #pragma unroll
            for (int h = 0; h < HID; ++h) s += q[h] * Ks[m][h];
            vals[i] = (m == n) ? -1.0e9f : s;
        }

        float mx = 0.f, my_val = 0.f, sum_exp = 0.f;
        int my_idx = 0;
        #pragma unroll
        for (int r = 0; r < TOPK; ++r) {
            float bv = vals[0];
            int   bi = lane;
            #pragma unroll
            for (int i = 1; i < 8; ++i) {
                const int m = i * 64 + lane;
                if (vals[i] > bv) { bv = vals[i]; bi = m; }
            }
            #pragma unroll
            for (int off = 32; off >= 1; off >>= 1) {
                const float ov = __shfl_xor(bv, off);
                const int   oi = __shfl_xor(bi, off);
                if (ov > bv || (ov == bv && oi < bi)) { bv = ov; bi = oi; }
            }
            if (r == 0) mx = bv;
            sum_exp += __expf(bv - mx);
            if (lane == r) { my_val = bv; my_idx = bi; }
            if ((bi & 63) == lane) {
                const int slot = bi >> 6;
                #pragma unroll
                for (int i = 0; i < 8; ++i)
                    if (slot == i) vals[i] = -3.4e38f;
            }
        }

        if (lane < TOPK) {
            g_idx[n * TOPK + lane] = my_idx;
            g_w[n * TOPK + lane]   = __expf(my_val - mx) / sum_exp;
        }

        __syncthreads();                 // all table writes done, Ks reads done
        if (t == 0) {
            __threadfence();             // release: publish table device-wide
            atomicExch(&flags[2 * blockIdx.x + 0], MAGIC0);
            atomicExch(&flags[2 * blockIdx.x + 1], MAGIC1);
        }
        // smem reuse below is safe: __syncthreads above separates Ks use.
    }

    // ---- wait for the routing chunk this block's columns need ----
    // thread t reads table rows for column n=t, produced by chunk t>>3.
    // Spin with one thread per chunk (t<64), then block barrier + acquire.
    if (t < 64) {
        long guard = 0;
        while (atomicAdd(&flags[2 * t + 0], 0u) != MAGIC0 ||
               atomicAdd(&flags[2 * t + 1], 0u) != MAGIC1) {
            __builtin_amdgcn_s_sleep(2);
            if (++guard > (1L << 27)) break;   // never expected; avoids hang
        }
    }
    __syncthreads();
    __threadfence();                     // acquire: invalidate stale L1/L2

    const int4   i0 = ((const int4*)g_idx)[2 * t + 0];
    const int4   i1 = ((const int4*)g_idx)[2 * t + 1];
    const float4 w0 = ((const float4*)g_w)[2 * t + 0];
    const float4 w1 = ((const float4*)g_w)[2 * t + 1];

    // ---- apply: R5 structure (8-row groups, double-buffered, lgkm-only barrier) ----
    float4* xs = reinterpret_cast<float4*>(smem);   // [buf*1024 + half*512 + col]

    #pragma unroll 1
    for (int g = 0; g < 4; ++g) {
        float4* buf = xs + (g & 1) * 1024;
        buf[t]       = make_float4(v0, v1, v2, v3);
        buf[512 + t] = make_float4(v4, v5, v6, v7);

        if (g < 3) {
            const float* xn = x + (base + 8 * (g + 1)) * NVARS + t;
            v0 = xn[0 * NVARS];
            v1 = xn[1 * NVARS];
            v2 = xn[2 * NVARS];
            v3 = xn[3 * NVARS];
            v4 = xn[4 * NVARS];
            v5 = xn[5 * NVARS];
            v6 = xn[6 * NVARS];
            v7 = xn[7 * NVARS];
        }

        asm volatile("s_waitcnt lgkmcnt(0)" ::: "memory");
        __builtin_amdgcn_s_barrier();
        asm volatile("" ::: "memory");

        float a0 = 0.f, a1 = 0.f, a2 = 0.f, a3 = 0.f;
        float a4 = 0.f, a5 = 0.f, a6 = 0.f, a7 = 0.f;
        float4 c0, c1;
#define GATH(II, WW)                                                        \
        c0 = buf[II]; c1 = buf[512 + (II)];                                 \
        a0 += c0.x * WW; a1 += c0.y * WW; a2 += c0.z * WW; a3 += c0.w * WW; \
        a4 += c1.x * WW; a5 += c1.y * WW; a6 += c1.z * WW; a7 += c1.w * WW;
        GATH(i0.x, w0.x)
        GATH(i0.y, w0.y)
        GATH(i0.z, w0.z)
        GATH(i0.w, w0.w)
        GATH(i1.x, w1.x)
        GATH(i1.y, w1.y)
        GATH(i1.z, w1.z)
        GATH(i1.w, w1.w)
#undef GATH

        float* o = out + (base + 8 * g) * NVARS + t;
        o[0 * NVARS] = a0;
        o[1 * NVARS] = a1;
        o[2 * NVARS] = a2;
        o[3 * NVARS] = a3;
        o[4 * NVARS] = a4;
        o[5 * NVARS] = a5;
        o[6 * NVARS] = a6;
        o[7 * NVARS] = a7;
        // no trailing barrier: next ds_writes hit the other buffer; same-
        // buffer WAR is separated by the next lgkm barrier.
    }
}

extern "C" void kernel_launch(void* const* d_in, const int* in_sizes, int n_in,
                              void* d_out, int out_size, void* d_ws, size_t ws_size,
                              hipStream_t stream) {
    const float* x  = (const float*)d_in[0];   // (8,4096,512)
    const float* ve = (const float*)d_in[1];   // (512,16)
    const float* Wq = (const float*)d_in[2];   // (16,16)
    const float* bq = (const float*)d_in[3];   // (16,)
    const float* Wk = (const float*)d_in[4];   // (16,16)
    const float* bk = (const float*)d_in[5];   // (16,)
    float* out = (float*)d_out;

    int*      idx_ws  = (int*)d_ws;
    float*    w_ws    = (float*)((char*)d_ws + NVARS * TOPK * sizeof(int));
    unsigned* flag_ws = (unsigned*)((char*)d_ws + 2 * NVARS * TOPK * sizeof(int));

    fused_kernel<<<1024, 512, 0, stream>>>(x, ve, Wq, bq, Wk, bk,
                                           idx_ws, w_ws, flag_ws, out);
}